// Round 4
// baseline (140.797 us; speedup 1.0000x reference)
//
#include <hip/hip_runtime.h>

typedef unsigned int uint;
typedef unsigned short ushort;
typedef __attribute__((ext_vector_type(8))) short short8;
typedef __attribute__((ext_vector_type(4))) float f32x4;
typedef __attribute__((ext_vector_type(4))) float float4v;
typedef __attribute__((ext_vector_type(4))) ushort ushort4v;

constexpr int Edim = 768;
constexpr int Kdim = 768;   // C*P*P
constexpr int Mdim = 25088; // B*Npatch
constexpr int BM = 256, BN = 128, BK = 64;
constexpr int KSTEPS = Kdim / BK;        // 12
constexpr int MB_TILES = Mdim / BM;      // 98
constexpr int EB_TILES = Edim / BN;      // 6
constexpr int NWG = MB_TILES * EB_TILES; // 588 (not /8 -> bijective swizzle)

// ws layout
constexpr size_t WS_AMAX = 0;
constexpr size_t WS_WSF = 1024;
constexpr size_t WS_BIAS = 4096;
constexpr size_t WS_WINT = 8192;           // 768*768*2
constexpr size_t WS_APAT = 8192 + 1179648; // 25088*768*2

// round-to-nearest-even f32 -> bf16
__device__ __forceinline__ ushort f2bf(float f) {
  uint u = __float_as_uint(f);
  return (ushort)((u + 0x7fffu + ((u >> 16) & 1u)) >> 16);
}

__device__ __forceinline__ void gload16(const ushort* g, ushort* l) {
  auto gp = (const __attribute__((address_space(1))) uint*)(const void*)g;
  auto lp = (__attribute__((address_space(3))) uint*)(void*)l;
  __builtin_amdgcn_global_load_lds(gp, lp, 16, 0, 0);
}

// ---------------- weight quantization ----------------
__global__ void prep_kernel(const float* __restrict__ weight,
                            const float* __restrict__ bias,
                            const float* __restrict__ sfin,
                            ushort* __restrict__ w_int,
                            float* __restrict__ w_sf,
                            float* __restrict__ bias_out) {
  __shared__ float red[256];
  const int e = blockIdx.x, t = threadIdx.x;
  const float* wrow = weight + e * Kdim;
  float mx = 0.f;
  for (int k = t; k < Kdim; k += 256) mx = fmaxf(mx, fabsf(wrow[k]));
  red[t] = mx;
  __syncthreads();
  for (int s = 128; s > 0; s >>= 1) {
    if (t < s) red[t] = fmaxf(red[t], red[t + s]);
    __syncthreads();
  }
  const float sf = red[0] / 127.0f;
  for (int k = t; k < Kdim; k += 256)
    w_int[e * Kdim + k] = f2bf(rintf(wrow[k] / sf));
  if (t == 0) {
    float conv = sf * sfin[0];
    w_sf[e] = sf;
    bias_out[e] = rintf(bias[e] / conv) * conv;
  }
}

// ---------------- patchify: x f32 -> A bf16 [M][K] ----------------
__global__ void patchify_kernel(const float* __restrict__ x,
                                ushort* __restrict__ A, int n4) {
  const int stride = gridDim.x * blockDim.x;
  for (int i4 = blockIdx.x * blockDim.x + threadIdx.x; i4 < n4; i4 += stride) {
    const int i = i4 * 4;
    const int w = i % 224;
    const int t1 = i / 224;
    const int h = t1 % 224;
    const int t2 = t1 / 224;
    const int c = t2 % 3;
    const int b = t2 / 3;
    float4v v = *(const float4v*)(x + i);
    ushort4v u;
    u.x = f2bf(v.x); u.y = f2bf(v.y); u.z = f2bf(v.z); u.w = f2bf(v.w);
    const int m = b * 196 + (h >> 4) * 14 + (w >> 4);
    const int d = c * 256 + (h & 15) * 16 + (w & 15);
    *(ushort4v*)(A + m * Kdim + d) = u;
  }
}

// ---------------- GEMM: 8-wave 256x128, 3-stage counted-vmcnt pipeline -------
// LDS logical [row][64] bf16; 16B chunk (row,cb) stored at chunk row*8+(cb^(row&7)).
// global_load_lds writes linearly -> pre-swizzle the global source (same involution).
// Pipeline: iter kb issues tile kb+2 -> stage (kb+2)%3, waits vmcnt(12) (2 tiles
// in flight), barrier, computes tile kb, barrier (protects stage kb%3 before the
// kb+1 iter's issue overwrites it). vmcnt never drains to 0 in the main loop.
__global__ __launch_bounds__(512, 2) void gemm3_kernel(
    const ushort* __restrict__ A, const ushort* __restrict__ Bw,
    const float* __restrict__ w_sf, const float* __restrict__ bias_out,
    float* __restrict__ out, uint* __restrict__ amax_bits) {
  __shared__ __align__(16) ushort As[3][BM * BK]; // 3 x 32 KB
  __shared__ __align__(16) ushort Bs[3][BN * BK]; // 3 x 16 KB  (total 144 KB)

  const int t = threadIdx.x;
  // bijective XCD swizzle for NWG=588 (588%8!=0 -> m204 variant)
  const int qq = NWG >> 3, r8 = NWG & 7;
  const int xcd = blockIdx.x & 7, bidx = blockIdx.x >> 3;
  const int wgid = (xcd < r8 ? xcd * (qq + 1) : r8 * (qq + 1) + (xcd - r8) * qq) + bidx;
  const int mb = wgid / EB_TILES;
  const int eb = wgid - mb * EB_TILES;
  const int m0 = mb * BM, e0 = eb * BN;

  // staging: linear LDS chunk c = r*512 + t; row = r*64 + (t>>3); slot s = t&7;
  // logical col cb = s ^ (row&7) = (t&7)^((t>>3)&7)
  const int cbs = (t & 7) ^ ((t >> 3) & 7);
  const ushort* ag = A + (size_t)(m0 + (t >> 3)) * Kdim + cbs * 8;
  const ushort* bg = Bw + (size_t)(e0 + (t >> 3)) * Kdim + cbs * 8;

  const int lane = t & 63;
  const int wv = t >> 6;               // 8 waves: 4M x 2N
  const int wrow0 = (wv >> 1) * 64;    // 0..192
  const int wcol0 = (wv & 1) * 64;     // 0/64
  const int l15 = lane & 15, l4 = lane >> 4;
  int arow[4], brow[4];
#pragma unroll
  for (int i = 0; i < 4; ++i) {
    arow[i] = wrow0 + i * 16 + l15;
    brow[i] = wcol0 + i * 16 + l15;
  }

  auto issue = [&](int kb, int st) {
    const ushort* agk = ag + kb * 64;
    const ushort* bgk = bg + kb * 64;
#pragma unroll
    for (int rr = 0; rr < 4; ++rr)
      gload16(agk + rr * 64 * Kdim, &As[st][(rr * 512 + t) * 8]);
#pragma unroll
    for (int rr = 0; rr < 2; ++rr)
      gload16(bgk + rr * 64 * Kdim, &Bs[st][(rr * 512 + t) * 8]);
  };

  f32x4 acc[4][4] = {};

  // prologue: 2 tiles in flight (12 loads)
  issue(0, 0);
  issue(1, 1);

#pragma unroll
  for (int kb = 0; kb < KSTEPS; ++kb) {
    const int st = kb % 3;
    if (kb + 2 < KSTEPS) issue(kb + 2, (kb + 2) % 3); // 6 more -> 18 in flight
    if (kb + 2 < KSTEPS)
      asm volatile("s_waitcnt vmcnt(12)" ::: "memory"); // tile kb landed
    else if (kb + 1 < KSTEPS)
      asm volatile("s_waitcnt vmcnt(6)" ::: "memory");
    else
      asm volatile("s_waitcnt vmcnt(0)" ::: "memory");
    __builtin_amdgcn_s_barrier(); // all waves' tile-kb loads are in LDS

#pragma unroll
    for (int kk = 0; kk < 2; ++kk) {
      short8 a[4], b[4];
      const int cb = kk * 4 + l4;
#pragma unroll
      for (int i = 0; i < 4; ++i)
        a[i] = *(const short8*)&As[st][arow[i] * 64 + ((cb ^ (arow[i] & 7)) << 3)];
#pragma unroll
      for (int i = 0; i < 4; ++i)
        b[i] = *(const short8*)&Bs[st][brow[i] * 64 + ((cb ^ (brow[i] & 7)) << 3)];
      __builtin_amdgcn_s_setprio(1);
#pragma unroll
      for (int mi = 0; mi < 4; ++mi)
#pragma unroll
        for (int ni = 0; ni < 4; ++ni)
          acc[mi][ni] = __builtin_amdgcn_mfma_f32_16x16x32_bf16(
              a[mi], b[ni], acc[mi][ni], 0, 0, 0);
      __builtin_amdgcn_s_setprio(0);
    }
    // all waves done READING stage st (their ds_reads completed before their
    // consuming MFMAs) -> next iter may overwrite it
    __builtin_amdgcn_s_barrier();
  }

  // epilogue: scale + bias, absmax, store f32
  float amax = 0.f;
#pragma unroll
  for (int ni = 0; ni < 4; ++ni) {
    const int e = e0 + wcol0 + ni * 16 + l15;
    const float s = w_sf[e], bo = bias_out[e];
#pragma unroll
    for (int mi = 0; mi < 4; ++mi) {
      const int mr = m0 + wrow0 + mi * 16 + l4 * 4;
#pragma unroll
      for (int q = 0; q < 4; ++q) {
        float v = acc[mi][ni][q] * s + bo;
        amax = fmaxf(amax, fabsf(v));
        out[(size_t)(mr + q) * Edim + e] = v;
      }
    }
  }
#pragma unroll
  for (int off = 32; off > 0; off >>= 1)
    amax = fmaxf(amax, __shfl_xor(amax, off));
  if (lane == 0) atomicMax(amax_bits, __float_as_uint(amax));
}

// ---------------- requantize in place + act_sf ----------------
__global__ void requant_kernel(float* __restrict__ out,
                               const uint* __restrict__ amax_bits,
                               float* __restrict__ sf_out, int n4) {
  const float mx = __uint_as_float(*amax_bits);
  const float act_sf = mx / 127.0f;
  const float inv = 127.0f / mx;
  const int idx = blockIdx.x * blockDim.x + threadIdx.x;
  if (idx == 0) *sf_out = act_sf;
  float4v* o = (float4v*)out;
  const int stride = gridDim.x * blockDim.x;
  for (int i = idx; i < n4; i += stride) {
    float4v v = o[i];
    v.x = rintf(v.x * inv) * act_sf;
    v.y = rintf(v.y * inv) * act_sf;
    v.z = rintf(v.z * inv) * act_sf;
    v.w = rintf(v.w * inv) * act_sf;
    o[i] = v;
  }
}

extern "C" void kernel_launch(void* const* d_in, const int* in_sizes, int n_in,
                              void* d_out, int out_size, void* d_ws, size_t ws_size,
                              hipStream_t stream) {
  const float* x = (const float*)d_in[0];
  const float* weight = (const float*)d_in[1];
  const float* bias = (const float*)d_in[2];
  const float* sfin = (const float*)d_in[3];
  float* out = (float*)d_out;

  char* ws = (char*)d_ws;
  uint* amax_bits = (uint*)(ws + WS_AMAX);
  float* w_sf = (float*)(ws + WS_WSF);
  float* bias_out = (float*)(ws + WS_BIAS);
  ushort* w_int = (ushort*)(ws + WS_WINT);
  ushort* A = (ushort*)(ws + WS_APAT);

  hipMemsetAsync(d_ws, 0, 4, stream);
  prep_kernel<<<Edim, 256, 0, stream>>>(weight, bias, sfin, w_int, w_sf, bias_out);

  const int n4 = (128 * 3 * 224 * 224) / 4;
  patchify_kernel<<<2048, 256, 0, stream>>>(x, A, n4);
  gemm3_kernel<<<NWG, 512, 0, stream>>>(A, w_int, w_sf, bias_out, out, amax_bits);

  const int n4o = (out_size - 1) / 4;
  requant_kernel<<<2048, 256, 0, stream>>>(out, amax_bits, out + (out_size - 1), n4o);
}

// Round 5
// 135.127 us; speedup vs baseline: 1.0420x; 1.0420x over previous
//
#include <hip/hip_runtime.h>

typedef unsigned int uint;
typedef unsigned short ushort;
typedef __attribute__((ext_vector_type(8))) short short8;
typedef __attribute__((ext_vector_type(4))) float f32x4;
typedef __attribute__((ext_vector_type(4))) float float4v;
typedef __attribute__((ext_vector_type(4))) ushort ushort4v;

constexpr int Edim = 768;
constexpr int Kdim = 768;   // C*P*P
constexpr int Mdim = 25088; // B*Npatch
constexpr int BM = 256, BN = 128, BK = 64;
constexpr int KSTEPS = Kdim / BK;        // 12
constexpr int MB_TILES = Mdim / BM;      // 98
constexpr int EB_TILES = Edim / BN;      // 6
constexpr int NWG = MB_TILES * EB_TILES; // 588

// ws layout
constexpr size_t WS_AMAX = 0;
constexpr size_t WS_WSF = 1024;
constexpr size_t WS_BIAS = 4096;
constexpr size_t WS_WINT = 8192;           // 768*768*2
constexpr size_t WS_APAT = 8192 + 1179648; // 25088*768*2

// round-to-nearest-even f32 -> bf16
__device__ __forceinline__ ushort f2bf(float f) {
  uint u = __float_as_uint(f);
  return (ushort)((u + 0x7fffu + ((u >> 16) & 1u)) >> 16);
}

__device__ __forceinline__ void gload16(const ushort* g, ushort* l) {
  auto gp = (const __attribute__((address_space(1))) uint*)(const void*)g;
  auto lp = (__attribute__((address_space(3))) uint*)(void*)l;
  __builtin_amdgcn_global_load_lds(gp, lp, 16, 0, 0);
}

// ---------------- weight quantization ----------------
__global__ void prep_kernel(const float* __restrict__ weight,
                            const float* __restrict__ bias,
                            const float* __restrict__ sfin,
                            ushort* __restrict__ w_int,
                            float* __restrict__ w_sf,
                            float* __restrict__ bias_out) {
  __shared__ float red[256];
  const int e = blockIdx.x, t = threadIdx.x;
  const float* wrow = weight + e * Kdim;
  float mx = 0.f;
  for (int k = t; k < Kdim; k += 256) mx = fmaxf(mx, fabsf(wrow[k]));
  red[t] = mx;
  __syncthreads();
  for (int s = 128; s > 0; s >>= 1) {
    if (t < s) red[t] = fmaxf(red[t], red[t + s]);
    __syncthreads();
  }
  const float sf = red[0] / 127.0f;
  for (int k = t; k < Kdim; k += 256)
    w_int[e * Kdim + k] = f2bf(rintf(wrow[k] / sf));
  if (t == 0) {
    float conv = sf * sfin[0];
    w_sf[e] = sf;
    bias_out[e] = rintf(bias[e] / conv) * conv;
  }
}

// ---------------- patchify: x f32 -> A bf16 [M][K] ----------------
__global__ void patchify_kernel(const float* __restrict__ x,
                                ushort* __restrict__ A, int n4) {
  const int stride = gridDim.x * blockDim.x;
  for (int i4 = blockIdx.x * blockDim.x + threadIdx.x; i4 < n4; i4 += stride) {
    const int i = i4 * 4;
    const int w = i % 224;
    const int t1 = i / 224;
    const int h = t1 % 224;
    const int t2 = t1 / 224;
    const int c = t2 % 3;
    const int b = t2 / 3;
    float4v v = *(const float4v*)(x + i);
    ushort4v u;
    u.x = f2bf(v.x); u.y = f2bf(v.y); u.z = f2bf(v.z); u.w = f2bf(v.w);
    const int m = b * 196 + (h >> 4) * 14 + (w >> 4);
    const int d = c * 256 + (h & 15) * 16 + (w & 15);
    *(ushort4v*)(A + m * Kdim + d) = u;
  }
}

// ---------------- GEMM: 8-wave 256x128, m201-style phase rhythm -------------
// 3 LDS stages (144 KB). Per K-tile = 2 phases (kk halves). Each phase:
//   {issue 3 stage-gloads of tile kb+2} {lgkmcnt(0)} {16 MFMA}  ... mid barrier
// End of tile: ONE combined {s_waitcnt vmcnt(6); s_barrier} -> tile kb+1 landed
// in ALL waves' LDS before any wave reads it. vmcnt never 0 in the main loop.
// Race proof: stage of tile kb+2 targets buf (kb+2)%3, last read by tile kb-1,
// whose readers all passed the end-of-(kb-1) barrier before this issue.
__global__ __launch_bounds__(512, 2) void gemm4_kernel(
    const ushort* __restrict__ A, const ushort* __restrict__ Bw,
    const float* __restrict__ w_sf, const float* __restrict__ bias_out,
    float* __restrict__ out, uint* __restrict__ amax_bits) {
  __shared__ __align__(16) ushort As[3][BM * BK]; // 3 x 32 KB
  __shared__ __align__(16) ushort Bs[3][BN * BK]; // 3 x 16 KB

  const int t = threadIdx.x;
  // bijective XCD swizzle for NWG=588 (588%8!=0 -> m204 variant)
  const int qq = NWG >> 3, r8 = NWG & 7;
  const int xcd = blockIdx.x & 7, bidx = blockIdx.x >> 3;
  const int wgid = (xcd < r8 ? xcd * (qq + 1) : r8 * (qq + 1) + (xcd - r8) * qq) + bidx;
  const int mb = wgid / EB_TILES;
  const int eb = wgid - mb * EB_TILES;
  const int m0 = mb * BM, e0 = eb * BN;

  // staging: linear LDS chunk c = rr*512 + t; row = rr*64 + (t>>3); slot s = t&7;
  // logical col cb = s ^ (row&7) = (t&7)^((t>>3)&7)  (involution: src pre-swizzled)
  const int cbs = (t & 7) ^ ((t >> 3) & 7);
  const ushort* ag = A + (size_t)(m0 + (t >> 3)) * Kdim + cbs * 8;
  const ushort* bg = Bw + (size_t)(e0 + (t >> 3)) * Kdim + cbs * 8;

  const int lane = t & 63;
  const int wv = t >> 6;            // 8 waves: 4M x 2N
  const int wrow0 = (wv >> 1) * 64; // 0..192
  const int wcol0 = (wv & 1) * 64;  // 0/64
  const int l15 = lane & 15, l4 = lane >> 4;
  int arow[4], brow[4];
#pragma unroll
  for (int i = 0; i < 4; ++i) {
    arow[i] = wrow0 + i * 16 + l15;
    brow[i] = wcol0 + i * 16 + l15;
  }

  f32x4 acc[4][4] = {};

  // prologue: tiles 0,1 (issue order per wave: tile0's 6 then tile1's 6)
#pragma unroll
  for (int pt = 0; pt < 2; ++pt) {
    const ushort* agk = ag + pt * 64;
#pragma unroll
    for (int rr = 0; rr < 4; ++rr)
      gload16(agk + rr * 64 * Kdim, &As[pt][(rr * 512 + t) * 8]);
#pragma unroll
    for (int rr = 0; rr < 2; ++rr)
      gload16(bg + pt * 64 + rr * 64 * Kdim, &Bs[pt][(rr * 512 + t) * 8]);
  }
  asm volatile("s_waitcnt vmcnt(6)\n\ts_barrier" ::: "memory"); // tile 0 landed (all waves)
  __builtin_amdgcn_sched_barrier(0);

#pragma unroll
  for (int kb = 0; kb < KSTEPS; ++kb) {
    const int st = kb % 3;
    const int st2 = (kb + 2) % 3;

    // ---------------- phase A (kk = 0) ----------------
    if (kb + 2 < KSTEPS) { // stage first half of tile kb+2
      const ushort* agk = ag + (kb + 2) * 64;
      gload16(agk + 0 * 64 * Kdim, &As[st2][(0 * 512 + t) * 8]);
      gload16(agk + 1 * 64 * Kdim, &As[st2][(1 * 512 + t) * 8]);
      gload16(bg + (kb + 2) * 64 + 0 * 64 * Kdim, &Bs[st2][(0 * 512 + t) * 8]);
    }
    short8 a0[4], b0[4];
    {
      const int cb = l4;
#pragma unroll
      for (int i = 0; i < 4; ++i)
        a0[i] = *(const short8*)&As[st][arow[i] * 64 + ((cb ^ (arow[i] & 7)) << 3)];
#pragma unroll
      for (int i = 0; i < 4; ++i)
        b0[i] = *(const short8*)&Bs[st][brow[i] * 64 + ((cb ^ (brow[i] & 7)) << 3)];
    }
    asm volatile("s_waitcnt lgkmcnt(0)" ::: "memory");
    __builtin_amdgcn_sched_barrier(0);
    __builtin_amdgcn_s_setprio(1);
#pragma unroll
    for (int mi = 0; mi < 4; ++mi)
#pragma unroll
      for (int ni = 0; ni < 4; ++ni)
        acc[mi][ni] = __builtin_amdgcn_mfma_f32_16x16x32_bf16(
            a0[mi], b0[ni], acc[mi][ni], 0, 0, 0);
    __builtin_amdgcn_s_setprio(0);
    // issue kk=1 reads BEFORE the mid barrier (same validated buffer; latency
    // overlaps barrier wait + other waves' MFMA tails)
    short8 a1[4], b1[4];
    {
      const int cb = 4 + l4;
#pragma unroll
      for (int i = 0; i < 4; ++i)
        a1[i] = *(const short8*)&As[st][arow[i] * 64 + ((cb ^ (arow[i] & 7)) << 3)];
#pragma unroll
      for (int i = 0; i < 4; ++i)
        b1[i] = *(const short8*)&Bs[st][brow[i] * 64 + ((cb ^ (brow[i] & 7)) << 3)];
    }
    __builtin_amdgcn_s_barrier(); // rhythm barrier (no drain)

    // ---------------- phase B (kk = 1) ----------------
    if (kb + 2 < KSTEPS) { // stage second half of tile kb+2
      const ushort* agk = ag + (kb + 2) * 64;
      gload16(agk + 2 * 64 * Kdim, &As[st2][(2 * 512 + t) * 8]);
      gload16(agk + 3 * 64 * Kdim, &As[st2][(3 * 512 + t) * 8]);
      gload16(bg + (kb + 2) * 64 + 1 * 64 * Kdim, &Bs[st2][(1 * 512 + t) * 8]);
    }
    asm volatile("s_waitcnt lgkmcnt(0)" ::: "memory");
    __builtin_amdgcn_sched_barrier(0);
    __builtin_amdgcn_s_setprio(1);
#pragma unroll
    for (int mi = 0; mi < 4; ++mi)
#pragma unroll
      for (int ni = 0; ni < 4; ++ni)
        acc[mi][ni] = __builtin_amdgcn_mfma_f32_16x16x32_bf16(
            a1[mi], b1[ni], acc[mi][ni], 0, 0, 0);
    __builtin_amdgcn_s_setprio(0);

    if (kb < KSTEPS - 1) {
      __builtin_amdgcn_sched_barrier(0);
      if (kb + 2 < KSTEPS) // allow the 6 newest (tile kb+2); tile kb+1 landed
        asm volatile("s_waitcnt vmcnt(6)\n\ts_barrier" ::: "memory");
      else                 // tail: nothing newer in flight
        asm volatile("s_waitcnt vmcnt(0)\n\ts_barrier" ::: "memory");
      __builtin_amdgcn_sched_barrier(0);
    }
  }

  // epilogue: scale + bias, absmax, store f32
  float amax = 0.f;
#pragma unroll
  for (int ni = 0; ni < 4; ++ni) {
    const int e = e0 + wcol0 + ni * 16 + l15;
    const float s = w_sf[e], bo = bias_out[e];
#pragma unroll
    for (int mi = 0; mi < 4; ++mi) {
      const int mr = m0 + wrow0 + mi * 16 + l4 * 4;
#pragma unroll
      for (int q = 0; q < 4; ++q) {
        float v = acc[mi][ni][q] * s + bo;
        amax = fmaxf(amax, fabsf(v));
        out[(size_t)(mr + q) * Edim + e] = v;
      }
    }
  }
#pragma unroll
  for (int off = 32; off > 0; off >>= 1)
    amax = fmaxf(amax, __shfl_xor(amax, off));
  if (lane == 0) atomicMax(amax_bits, __float_as_uint(amax));
}

// ---------------- requantize in place + act_sf ----------------
__global__ void requant_kernel(float* __restrict__ out,
                               const uint* __restrict__ amax_bits,
                               float* __restrict__ sf_out, int n4) {
  const float mx = __uint_as_float(*amax_bits);
  const float act_sf = mx / 127.0f;
  const float inv = 127.0f / mx;
  const int idx = blockIdx.x * blockDim.x + threadIdx.x;
  if (idx == 0) *sf_out = act_sf;
  float4v* o = (float4v*)out;
  const int stride = gridDim.x * blockDim.x;
  for (int i = idx; i < n4; i += stride) {
    float4v v = o[i];
    v.x = rintf(v.x * inv) * act_sf;
    v.y = rintf(v.y * inv) * act_sf;
    v.z = rintf(v.z * inv) * act_sf;
    v.w = rintf(v.w * inv) * act_sf;
    o[i] = v;
  }
}

extern "C" void kernel_launch(void* const* d_in, const int* in_sizes, int n_in,
                              void* d_out, int out_size, void* d_ws, size_t ws_size,
                              hipStream_t stream) {
  const float* x = (const float*)d_in[0];
  const float* weight = (const float*)d_in[1];
  const float* bias = (const float*)d_in[2];
  const float* sfin = (const float*)d_in[3];
  float* out = (float*)d_out;

  char* ws = (char*)d_ws;
  uint* amax_bits = (uint*)(ws + WS_AMAX);
  float* w_sf = (float*)(ws + WS_WSF);
  float* bias_out = (float*)(ws + WS_BIAS);
  ushort* w_int = (ushort*)(ws + WS_WINT);
  ushort* A = (ushort*)(ws + WS_APAT);

  hipMemsetAsync(d_ws, 0, 4, stream);
  prep_kernel<<<Edim, 256, 0, stream>>>(weight, bias, sfin, w_int, w_sf, bias_out);

  const int n4 = (128 * 3 * 224 * 224) / 4;
  patchify_kernel<<<2048, 256, 0, stream>>>(x, A, n4);
  gemm4_kernel<<<NWG, 512, 0, stream>>>(A, w_int, w_sf, bias_out, out, amax_bits);

  const int n4o = (out_size - 1) / 4;
  requant_kernel<<<2048, 256, 0, stream>>>(out, amax_bits, out + (out_size - 1), n4o);
}

// Round 6
// 102.420 us; speedup vs baseline: 1.3747x; 1.3193x over previous
//
#include <hip/hip_runtime.h>

typedef unsigned int uint;
typedef unsigned short ushort;
typedef __attribute__((ext_vector_type(8))) short short8;
typedef __attribute__((ext_vector_type(4))) float f32x4;
typedef __attribute__((ext_vector_type(4))) float float4v;
typedef __attribute__((ext_vector_type(4))) ushort ushort4v;

constexpr int Edim = 768;
constexpr int Kdim = 768;   // C*P*P
constexpr int Mdim = 25088; // B*Npatch
constexpr int BM = 128, BN = 128, BK = 64;
constexpr int KSTEPS = Kdim / BK;        // 12
constexpr int MB_TILES = Mdim / BM;      // 196
constexpr int EB_TILES = Edim / BN;      // 6
constexpr int NWG = MB_TILES * EB_TILES; // 1176 = 8*147

// ws layout
constexpr size_t WS_AMAXARR = 0;            // NWG floats (per-block amax, plain stores)
constexpr size_t WS_WSF = 8192;
constexpr size_t WS_BIAS = 12288;
constexpr size_t WS_WINT = 16384;           // 768*768*2
constexpr size_t WS_APAT = 16384 + 1179648; // 25088*768*2

// round-to-nearest-even f32 -> bf16
__device__ __forceinline__ ushort f2bf(float f) {
  uint u = __float_as_uint(f);
  return (ushort)((u + 0x7fffu + ((u >> 16) & 1u)) >> 16);
}

__device__ __forceinline__ void gload16(const ushort* g, ushort* l) {
  auto gp = (const __attribute__((address_space(1))) uint*)(const void*)g;
  auto lp = (__attribute__((address_space(3))) uint*)(void*)l;
  __builtin_amdgcn_global_load_lds(gp, lp, 16, 0, 0);
}

// ---------------- weight quantization ----------------
__global__ void prep_kernel(const float* __restrict__ weight,
                            const float* __restrict__ bias,
                            const float* __restrict__ sfin,
                            ushort* __restrict__ w_int,
                            float* __restrict__ w_sf,
                            float* __restrict__ bias_out) {
  __shared__ float red[256];
  const int e = blockIdx.x, t = threadIdx.x;
  const float* wrow = weight + e * Kdim;
  float mx = 0.f;
  for (int k = t; k < Kdim; k += 256) mx = fmaxf(mx, fabsf(wrow[k]));
  red[t] = mx;
  __syncthreads();
  for (int s = 128; s > 0; s >>= 1) {
    if (t < s) red[t] = fmaxf(red[t], red[t + s]);
    __syncthreads();
  }
  const float sf = red[0] / 127.0f;
  for (int k = t; k < Kdim; k += 256)
    w_int[e * Kdim + k] = f2bf(rintf(wrow[k] / sf));
  if (t == 0) {
    float conv = sf * sfin[0];
    w_sf[e] = sf;
    bias_out[e] = rintf(bias[e] / conv) * conv;
  }
}

// ---------------- patchify: x f32 -> A bf16 [M][K] ----------------
__global__ void patchify_kernel(const float* __restrict__ x,
                                ushort* __restrict__ A, int n4) {
  const int stride = gridDim.x * blockDim.x;
  for (int i4 = blockIdx.x * blockDim.x + threadIdx.x; i4 < n4; i4 += stride) {
    const int i = i4 * 4;
    const int w = i % 224;
    const int t1 = i / 224;
    const int h = t1 % 224;
    const int t2 = t1 / 224;
    const int c = t2 % 3;
    const int b = t2 / 3;
    float4v v = *(const float4v*)(x + i);
    ushort4v u;
    u.x = f2bf(v.x); u.y = f2bf(v.y); u.z = f2bf(v.z); u.w = f2bf(v.w);
    const int m = b * 196 + (h >> 4) * 14 + (w >> 4);
    const int d = c * 256 + (h & 15) * 16 + (w & 15);
    *(ushort4v*)(A + m * Kdim + d) = u;
  }
}

// ---------------- GEMM: 2-phase double-buffered (round-3 structure), NO atomics
__global__ __launch_bounds__(256) void gemm2_kernel(
    const ushort* __restrict__ A, const ushort* __restrict__ Bw,
    const float* __restrict__ w_sf, const float* __restrict__ bias_out,
    float* __restrict__ out, float* __restrict__ amax_arr) {
  __shared__ __align__(16) ushort As[2][BM * BK];
  __shared__ __align__(16) ushort Bs[2][BN * BK];
  __shared__ float sred[4];

  const int t = threadIdx.x;
  // bijective XCD swizzle (NWG = 1176 = 8*147)
  const int orig = blockIdx.x;
  const int swz = (orig & 7) * (NWG / 8) + (orig >> 3);
  const int mb = swz / EB_TILES;
  const int eb = swz - mb * EB_TILES;
  const int m0 = mb * BM;
  const int e0 = eb * BN;

  // staging: linear LDS chunk c = r*256 + t; row = r*32 + (t>>3);
  // stored slot s = t&7; logical col cb = s ^ (row&7) = (t&7)^((t>>3)&7)
  const int cbs = (t & 7) ^ ((t >> 3) & 7);
  const ushort* ag = A + (size_t)(m0 + (t >> 3)) * Kdim + cbs * 8;
  const ushort* bg = Bw + (size_t)(e0 + (t >> 3)) * Kdim + cbs * 8;

  const int lane = t & 63;
  const int wv = t >> 6;
  const int wrow0 = (wv >> 1) * 64;
  const int wcol0 = (wv & 1) * 64;
  const int l15 = lane & 15, l4 = lane >> 4;
  int arow[4], brow[4];
#pragma unroll
  for (int i = 0; i < 4; ++i) {
    arow[i] = wrow0 + i * 16 + l15;
    brow[i] = wcol0 + i * 16 + l15;
  }

  f32x4 acc[4][4] = {};

  // prologue: stage tile 0 into buffer 0
#pragma unroll
  for (int r = 0; r < 4; ++r) {
    gload16(ag + r * 32 * Kdim, &As[0][(r * 256 + t) * 8]);
    gload16(bg + r * 32 * Kdim, &Bs[0][(r * 256 + t) * 8]);
  }
  __syncthreads();

#pragma unroll 2
  for (int kb = 0; kb < KSTEPS; ++kb) {
    const int cur = kb & 1;
    // issue next-tile loads FIRST (latency hides under this tile's compute)
    if (kb + 1 < KSTEPS) {
#pragma unroll
      for (int r = 0; r < 4; ++r) {
        gload16(ag + (kb + 1) * 64 + r * 32 * Kdim, &As[cur ^ 1][(r * 256 + t) * 8]);
        gload16(bg + (kb + 1) * 64 + r * 32 * Kdim, &Bs[cur ^ 1][(r * 256 + t) * 8]);
      }
    }
    // compute current tile
#pragma unroll
    for (int kk = 0; kk < 2; ++kk) {
      short8 a[4], b[4];
      const int cb = kk * 4 + l4;
#pragma unroll
      for (int i = 0; i < 4; ++i)
        a[i] = *(const short8*)&As[cur][arow[i] * 64 + ((cb ^ (arow[i] & 7)) << 3)];
#pragma unroll
      for (int i = 0; i < 4; ++i)
        b[i] = *(const short8*)&Bs[cur][brow[i] * 64 + ((cb ^ (brow[i] & 7)) << 3)];
#pragma unroll
      for (int mi = 0; mi < 4; ++mi)
#pragma unroll
        for (int ni = 0; ni < 4; ++ni)
          acc[mi][ni] = __builtin_amdgcn_mfma_f32_16x16x32_bf16(
              a[mi], b[ni], acc[mi][ni], 0, 0, 0);
    }
    // single barrier per K-step: drains prefetch + guards buffer reuse
    __syncthreads();
  }

  // epilogue: scale + bias, absmax, store f32
  float amax = 0.f;
#pragma unroll
  for (int ni = 0; ni < 4; ++ni) {
    const int e = e0 + wcol0 + ni * 16 + l15;
    const float s = w_sf[e], bo = bias_out[e];
#pragma unroll
    for (int mi = 0; mi < 4; ++mi) {
      const int mr = m0 + wrow0 + mi * 16 + l4 * 4;
#pragma unroll
      for (int q = 0; q < 4; ++q) {
        float v = acc[mi][ni][q] * s + bo;
        amax = fmaxf(amax, fabsf(v));
        out[(size_t)(mr + q) * Edim + e] = v;
      }
    }
  }
  // per-block reduce -> ONE plain store (no atomics anywhere)
#pragma unroll
  for (int off = 32; off > 0; off >>= 1)
    amax = fmaxf(amax, __shfl_xor(amax, off));
  if (lane == 0) sred[wv] = amax;
  __syncthreads();
  if (t == 0)
    amax_arr[orig] = fmaxf(fmaxf(sred[0], sred[1]), fmaxf(sred[2], sred[3]));
}

// ---------------- requantize: reduce per-block amax array, then rescale -----
__global__ void requant_kernel(float* __restrict__ out,
                               const float* __restrict__ amax_arr,
                               float* __restrict__ sf_out, int n4) {
  __shared__ float smax[4];
  const int t = threadIdx.x;
  float m = 0.f;
  for (int i = t; i < NWG; i += 256) m = fmaxf(m, amax_arr[i]);
#pragma unroll
  for (int off = 32; off > 0; off >>= 1) m = fmaxf(m, __shfl_xor(m, off));
  if ((t & 63) == 0) smax[t >> 6] = m;
  __syncthreads();
  m = fmaxf(fmaxf(smax[0], smax[1]), fmaxf(smax[2], smax[3]));

  const float act_sf = m / 127.0f;
  const float inv = 127.0f / m;
  const int idx = blockIdx.x * blockDim.x + t;
  if (idx == 0) *sf_out = act_sf;
  float4v* o = (float4v*)out;
  const int stride = gridDim.x * blockDim.x;
  for (int i = idx; i < n4; i += stride) {
    float4v v = o[i];
    v.x = rintf(v.x * inv) * act_sf;
    v.y = rintf(v.y * inv) * act_sf;
    v.z = rintf(v.z * inv) * act_sf;
    v.w = rintf(v.w * inv) * act_sf;
    o[i] = v;
  }
}

extern "C" void kernel_launch(void* const* d_in, const int* in_sizes, int n_in,
                              void* d_out, int out_size, void* d_ws, size_t ws_size,
                              hipStream_t stream) {
  const float* x = (const float*)d_in[0];
  const float* weight = (const float*)d_in[1];
  const float* bias = (const float*)d_in[2];
  const float* sfin = (const float*)d_in[3];
  float* out = (float*)d_out;

  char* ws = (char*)d_ws;
  float* amax_arr = (float*)(ws + WS_AMAXARR);
  float* w_sf = (float*)(ws + WS_WSF);
  float* bias_out = (float*)(ws + WS_BIAS);
  ushort* w_int = (ushort*)(ws + WS_WINT);
  ushort* A = (ushort*)(ws + WS_APAT);

  prep_kernel<<<Edim, 256, 0, stream>>>(weight, bias, sfin, w_int, w_sf, bias_out);

  const int n4 = (128 * 3 * 224 * 224) / 4;
  patchify_kernel<<<2048, 256, 0, stream>>>(x, A, n4);
  gemm2_kernel<<<NWG, 256, 0, stream>>>(A, w_int, w_sf, bias_out, out, amax_arr);

  const int n4o = (out_size - 1) / 4;
  requant_kernel<<<2048, 256, 0, stream>>>(out, amax_arr, out + (out_size - 1), n4o);
}

// Round 7
// 100.087 us; speedup vs baseline: 1.4068x; 1.0233x over previous
//
#include <hip/hip_runtime.h>

typedef unsigned int uint;
typedef unsigned short ushort;
typedef __attribute__((ext_vector_type(8))) short short8;
typedef __attribute__((ext_vector_type(4))) float f32x4;
typedef __attribute__((ext_vector_type(4))) float float4v;
typedef __attribute__((ext_vector_type(4))) ushort ushort4v;

constexpr int Edim = 768;
constexpr int Kdim = 768;   // C*P*P
constexpr int Mdim = 25088; // B*Npatch
constexpr int BM = 256, BN = 128, BK = 64;
constexpr int KSTEPS = Kdim / BK;        // 12
constexpr int MB_TILES = Mdim / BM;      // 98
constexpr int EB_TILES = Edim / BN;      // 6
constexpr int NWG = MB_TILES * EB_TILES; // 588

// ws layout
constexpr size_t WS_AMAXARR = 0;            // NWG floats (per-block amax, plain stores)
constexpr size_t WS_WSF = 8192;
constexpr size_t WS_BIAS = 12288;
constexpr size_t WS_WINT = 16384;           // 768*768*2
constexpr size_t WS_APAT = 16384 + 1179648; // 25088*768*2

// round-to-nearest-even f32 -> bf16
__device__ __forceinline__ ushort f2bf(float f) {
  uint u = __float_as_uint(f);
  return (ushort)((u + 0x7fffu + ((u >> 16) & 1u)) >> 16);
}

__device__ __forceinline__ void gload16(const ushort* g, ushort* l) {
  auto gp = (const __attribute__((address_space(1))) uint*)(const void*)g;
  auto lp = (__attribute__((address_space(3))) uint*)(void*)l;
  __builtin_amdgcn_global_load_lds(gp, lp, 16, 0, 0);
}

// ---------------- weight quantization ----------------
__global__ void prep_kernel(const float* __restrict__ weight,
                            const float* __restrict__ bias,
                            const float* __restrict__ sfin,
                            ushort* __restrict__ w_int,
                            float* __restrict__ w_sf,
                            float* __restrict__ bias_out) {
  __shared__ float red[256];
  const int e = blockIdx.x, t = threadIdx.x;
  const float* wrow = weight + e * Kdim;
  float mx = 0.f;
  for (int k = t; k < Kdim; k += 256) mx = fmaxf(mx, fabsf(wrow[k]));
  red[t] = mx;
  __syncthreads();
  for (int s = 128; s > 0; s >>= 1) {
    if (t < s) red[t] = fmaxf(red[t], red[t + s]);
    __syncthreads();
  }
  const float sf = red[0] / 127.0f;
  for (int k = t; k < Kdim; k += 256)
    w_int[e * Kdim + k] = f2bf(rintf(wrow[k] / sf));
  if (t == 0) {
    float conv = sf * sfin[0];
    w_sf[e] = sf;
    bias_out[e] = rintf(bias[e] / conv) * conv;
  }
}

// ---------------- patchify: x f32 -> A bf16 [M][K] ----------------
__global__ void patchify_kernel(const float* __restrict__ x,
                                ushort* __restrict__ A, int n4) {
  const int stride = gridDim.x * blockDim.x;
  for (int i4 = blockIdx.x * blockDim.x + threadIdx.x; i4 < n4; i4 += stride) {
    const int i = i4 * 4;
    const int w = i % 224;
    const int t1 = i / 224;
    const int h = t1 % 224;
    const int t2 = t1 / 224;
    const int c = t2 % 3;
    const int b = t2 / 3;
    float4v v = *(const float4v*)(x + i);
    ushort4v u;
    u.x = f2bf(v.x); u.y = f2bf(v.y); u.z = f2bf(v.z); u.w = f2bf(v.w);
    const int m = b * 196 + (h >> 4) * 14 + (w >> 4);
    const int d = c * 256 + (h & 15) * 16 + (w & 15);
    *(ushort4v*)(A + m * Kdim + d) = u;
  }
}

// ---------------- GEMM: 8-wave 256x128, fine-phase counted-vmcnt, NO atomics -
// 3 LDS stages (144 KB). Per K-tile = 2 phases (kk halves). Each phase:
//   {issue 3 stage-gloads of tile kb+2} {ds_read frag} {lgkmcnt(0)} {16 MFMA}
// End of tile: ONE combined {s_waitcnt vmcnt(6); s_barrier} -> tile kb+1 landed
// in ALL waves' LDS before any wave reads it. vmcnt never 0 in the main loop.
// Race proof: stage of tile kb+2 targets buf (kb+2)%3, last read by tile kb-1,
// whose readers all passed the end-of-(kb-1) barrier before this issue.
__global__ __launch_bounds__(512, 2) void gemm4_kernel(
    const ushort* __restrict__ A, const ushort* __restrict__ Bw,
    const float* __restrict__ w_sf, const float* __restrict__ bias_out,
    float* __restrict__ out, float* __restrict__ amax_arr) {
  __shared__ __align__(16) ushort As[3][BM * BK]; // 3 x 32 KB
  __shared__ __align__(16) ushort Bs[3][BN * BK]; // 3 x 16 KB
  __shared__ float sred[8];

  const int t = threadIdx.x;
  // bijective XCD swizzle for NWG=588 (588%8!=0 -> m204 variant)
  const int qq = NWG >> 3, r8 = NWG & 7;
  const int xcd = blockIdx.x & 7, bidx = blockIdx.x >> 3;
  const int wgid = (xcd < r8 ? xcd * (qq + 1) : r8 * (qq + 1) + (xcd - r8) * qq) + bidx;
  const int mb = wgid / EB_TILES;
  const int eb = wgid - mb * EB_TILES;
  const int m0 = mb * BM, e0 = eb * BN;

  // staging: linear LDS chunk c = rr*512 + t; row = rr*64 + (t>>3); slot s = t&7;
  // logical col cb = s ^ (row&7) = (t&7)^((t>>3)&7)  (involution: src pre-swizzled)
  const int cbs = (t & 7) ^ ((t >> 3) & 7);
  const ushort* ag = A + (size_t)(m0 + (t >> 3)) * Kdim + cbs * 8;
  const ushort* bg = Bw + (size_t)(e0 + (t >> 3)) * Kdim + cbs * 8;

  const int lane = t & 63;
  const int wv = t >> 6;            // 8 waves: 4M x 2N
  const int wrow0 = (wv >> 1) * 64; // 0..192
  const int wcol0 = (wv & 1) * 64;  // 0/64
  const int l15 = lane & 15, l4 = lane >> 4;
  int arow[4], brow[4];
#pragma unroll
  for (int i = 0; i < 4; ++i) {
    arow[i] = wrow0 + i * 16 + l15;
    brow[i] = wcol0 + i * 16 + l15;
  }

  f32x4 acc[4][4] = {};

  // prologue: tiles 0,1
#pragma unroll
  for (int pt = 0; pt < 2; ++pt) {
    const ushort* agk = ag + pt * 64;
#pragma unroll
    for (int rr = 0; rr < 4; ++rr)
      gload16(agk + rr * 64 * Kdim, &As[pt][(rr * 512 + t) * 8]);
#pragma unroll
    for (int rr = 0; rr < 2; ++rr)
      gload16(bg + pt * 64 + rr * 64 * Kdim, &Bs[pt][(rr * 512 + t) * 8]);
  }
  asm volatile("s_waitcnt vmcnt(6)\n\ts_barrier" ::: "memory"); // tile 0 landed
  __builtin_amdgcn_sched_barrier(0);

#pragma unroll
  for (int kb = 0; kb < KSTEPS; ++kb) {
    const int st = kb % 3;
    const int st2 = (kb + 2) % 3;

    // ---------------- phase A (kk = 0) ----------------
    if (kb + 2 < KSTEPS) { // stage first half of tile kb+2
      const ushort* agk = ag + (kb + 2) * 64;
      gload16(agk + 0 * 64 * Kdim, &As[st2][(0 * 512 + t) * 8]);
      gload16(agk + 1 * 64 * Kdim, &As[st2][(1 * 512 + t) * 8]);
      gload16(bg + (kb + 2) * 64 + 0 * 64 * Kdim, &Bs[st2][(0 * 512 + t) * 8]);
    }
    short8 a0[4], b0[4];
    {
      const int cb = l4;
#pragma unroll
      for (int i = 0; i < 4; ++i)
        a0[i] = *(const short8*)&As[st][arow[i] * 64 + ((cb ^ (arow[i] & 7)) << 3)];
#pragma unroll
      for (int i = 0; i < 4; ++i)
        b0[i] = *(const short8*)&Bs[st][brow[i] * 64 + ((cb ^ (brow[i] & 7)) << 3)];
    }
    asm volatile("s_waitcnt lgkmcnt(0)" ::: "memory");
    __builtin_amdgcn_sched_barrier(0);
    __builtin_amdgcn_s_setprio(1);
#pragma unroll
    for (int mi = 0; mi < 4; ++mi)
#pragma unroll
      for (int ni = 0; ni < 4; ++ni)
        acc[mi][ni] = __builtin_amdgcn_mfma_f32_16x16x32_bf16(
            a0[mi], b0[ni], acc[mi][ni], 0, 0, 0);
    __builtin_amdgcn_s_setprio(0);
    // issue kk=1 reads BEFORE the mid barrier (same validated buffer)
    short8 a1[4], b1[4];
    {
      const int cb = 4 + l4;
#pragma unroll
      for (int i = 0; i < 4; ++i)
        a1[i] = *(const short8*)&As[st][arow[i] * 64 + ((cb ^ (arow[i] & 7)) << 3)];
#pragma unroll
      for (int i = 0; i < 4; ++i)
        b1[i] = *(const short8*)&Bs[st][brow[i] * 64 + ((cb ^ (brow[i] & 7)) << 3)];
    }
    __builtin_amdgcn_s_barrier(); // rhythm barrier (no drain)

    // ---------------- phase B (kk = 1) ----------------
    if (kb + 2 < KSTEPS) { // stage second half of tile kb+2
      const ushort* agk = ag + (kb + 2) * 64;
      gload16(agk + 2 * 64 * Kdim, &As[st2][(2 * 512 + t) * 8]);
      gload16(agk + 3 * 64 * Kdim, &As[st2][(3 * 512 + t) * 8]);
      gload16(bg + (kb + 2) * 64 + 1 * 64 * Kdim, &Bs[st2][(1 * 512 + t) * 8]);
    }
    asm volatile("s_waitcnt lgkmcnt(0)" ::: "memory");
    __builtin_amdgcn_sched_barrier(0);
    __builtin_amdgcn_s_setprio(1);
#pragma unroll
    for (int mi = 0; mi < 4; ++mi)
#pragma unroll
      for (int ni = 0; ni < 4; ++ni)
        acc[mi][ni] = __builtin_amdgcn_mfma_f32_16x16x32_bf16(
            a1[mi], b1[ni], acc[mi][ni], 0, 0, 0);
    __builtin_amdgcn_s_setprio(0);

    if (kb < KSTEPS - 1) {
      __builtin_amdgcn_sched_barrier(0);
      if (kb + 2 < KSTEPS) // allow the 6 newest (tile kb+2); tile kb+1 landed
        asm volatile("s_waitcnt vmcnt(6)\n\ts_barrier" ::: "memory");
      else                 // tail: nothing newer in flight
        asm volatile("s_waitcnt vmcnt(0)\n\ts_barrier" ::: "memory");
      __builtin_amdgcn_sched_barrier(0);
    }
  }

  // epilogue: scale + bias, absmax, store f32
  float amax = 0.f;
#pragma unroll
  for (int ni = 0; ni < 4; ++ni) {
    const int e = e0 + wcol0 + ni * 16 + l15;
    const float s = w_sf[e], bo = bias_out[e];
#pragma unroll
    for (int mi = 0; mi < 4; ++mi) {
      const int mr = m0 + wrow0 + mi * 16 + l4 * 4;
#pragma unroll
      for (int q = 0; q < 4; ++q) {
        float v = acc[mi][ni][q] * s + bo;
        amax = fmaxf(amax, fabsf(v));
        out[(size_t)(mr + q) * Edim + e] = v;
      }
    }
  }
  // per-block reduce -> ONE plain store (no atomics anywhere)
#pragma unroll
  for (int off = 32; off > 0; off >>= 1)
    amax = fmaxf(amax, __shfl_xor(amax, off));
  if (lane == 0) sred[wv] = amax;
  __syncthreads();
  if (t == 0) {
    float m = sred[0];
#pragma unroll
    for (int i = 1; i < 8; ++i) m = fmaxf(m, sred[i]);
    amax_arr[blockIdx.x] = m;
  }
}

// ---------------- requantize: reduce per-block amax array, then rescale -----
__global__ void requant_kernel(float* __restrict__ out,
                               const float* __restrict__ amax_arr,
                               float* __restrict__ sf_out, int n4) {
  __shared__ float smax[4];
  const int t = threadIdx.x;
  float m = 0.f;
  for (int i = t; i < NWG; i += 256) m = fmaxf(m, amax_arr[i]);
#pragma unroll
  for (int off = 32; off > 0; off >>= 1) m = fmaxf(m, __shfl_xor(m, off));
  if ((t & 63) == 0) smax[t >> 6] = m;
  __syncthreads();
  m = fmaxf(fmaxf(smax[0], smax[1]), fmaxf(smax[2], smax[3]));

  const float act_sf = m / 127.0f;
  const float inv = 127.0f / m;
  const int idx = blockIdx.x * blockDim.x + t;
  if (idx == 0) *sf_out = act_sf;
  float4v* o = (float4v*)out;
  const int stride = gridDim.x * blockDim.x;
  for (int i = idx; i < n4; i += stride) {
    float4v v = o[i];
    v.x = rintf(v.x * inv) * act_sf;
    v.y = rintf(v.y * inv) * act_sf;
    v.z = rintf(v.z * inv) * act_sf;
    v.w = rintf(v.w * inv) * act_sf;
    o[i] = v;
  }
}

extern "C" void kernel_launch(void* const* d_in, const int* in_sizes, int n_in,
                              void* d_out, int out_size, void* d_ws, size_t ws_size,
                              hipStream_t stream) {
  const float* x = (const float*)d_in[0];
  const float* weight = (const float*)d_in[1];
  const float* bias = (const float*)d_in[2];
  const float* sfin = (const float*)d_in[3];
  float* out = (float*)d_out;

  char* ws = (char*)d_ws;
  float* amax_arr = (float*)(ws + WS_AMAXARR);
  float* w_sf = (float*)(ws + WS_WSF);
  float* bias_out = (float*)(ws + WS_BIAS);
  ushort* w_int = (ushort*)(ws + WS_WINT);
  ushort* A = (ushort*)(ws + WS_APAT);

  prep_kernel<<<Edim, 256, 0, stream>>>(weight, bias, sfin, w_int, w_sf, bias_out);

  const int n4 = (128 * 3 * 224 * 224) / 4;
  patchify_kernel<<<2048, 256, 0, stream>>>(x, A, n4);
  gemm4_kernel<<<NWG, 512, 0, stream>>>(A, w_int, w_sf, bias_out, out, amax_arr);

  const int n4o = (out_size - 1) / 4;
  requant_kernel<<<2048, 256, 0, stream>>>(out, amax_arr, out + (out_size - 1), n4o);
}